// Round 8
// baseline (417.485 us; speedup 1.0000x reference)
//
#include <hip/hip_runtime.h>
#include <stdint.h>

#define B_ 2
#define N_ 4096
#define KNN 16
#define D_ 256
#define EPS_ 1e-5f
#define COLS_TOTAL (B_ * N_ * KNN)   // 131072
#define LOGNCHK 4

typedef unsigned short u16;
typedef unsigned long long u64;
typedef __bf16 bf16x8 __attribute__((ext_vector_type(8)));
typedef float f32x4 __attribute__((ext_vector_type(4)));

__device__ __forceinline__ float bu2f(u16 u) { return __uint_as_float(((unsigned)u) << 16); }
__device__ __forceinline__ u16 f2bu(float f) {
  __bf16 h = (__bf16)f;                      // RNE via v_cvt_pk_bf16_f32
  return __builtin_bit_cast(unsigned short, h);
}
__device__ __forceinline__ float rdl(const void* p, size_t i, int f) {
  return f ? bu2f(((const u16*)p)[i]) : ((const float*)p)[i];
}

// ---------- scal (canonical f32) offsets ----------
#define SC_POS 0
#define SC_BLSQ 24576
#define SC_BLSO 24832
#define SC_BK 25088
#define SC_BQ 25344
#define SC_BV 25600
#define SC_WP1 25856
#define SC_BP1 26048
#define SC_G1 26112
#define SC_BT1 26176
#define SC_M1 26240
#define SC_V1 26304
#define SC_BP2 26368
#define SC_BA1 26624
#define SC_G2 27648
#define SC_BT2 28672
#define SC_M2 29696
#define SC_V2 30720
#define SC_BA2 31744
#define SC_BFIN 32000
#define SC_BQP 32128
#define SC_BKP 32384
#define SC_BVP 32640
#define SC_W1S 32896
#define SC_C1  33088
#define SC_ASC 33152
#define SC_ASH 34176
#define SC_TOT 35200

// ---------- ingest (with inline dtype detect) ----------
#define NSEG 29
struct Seg { const void* s; float* d; int n; };
struct SegTab { Seg seg[NSEG]; };
__global__ void ingest(SegTab t, const unsigned* __restrict__ praw,
                       int* __restrict__ flagp, int total) {
  __shared__ int cnt;
  if (threadIdx.x == 0) cnt = 0;
  __syncthreads();
  unsigned wv = praw[threadIdx.x];
  unsigned e = (wv >> 7) & 0xFFu;
  if (e >= 0x7Au && e <= 0x81u) atomicAdd(&cnt, 1);
  __syncthreads();
  int f = (cnt >= 128) ? 1 : 0;
  if (blockIdx.x == 0 && threadIdx.x == 0) *flagp = f;
  int tid = blockIdx.x * blockDim.x + threadIdx.x;
  if (tid >= total) return;
  int acc = 0, k = 0;
  for (k = 0; k < NSEG; k++) { if (tid < acc + t.seg[k].n) break; acc += t.seg[k].n; }
  int i = tid - acc;
  t.seg[k].d[i] = rdl(t.seg[k].s, i, f);
}

// ---------- device bodies for fused prep kernels ----------
__device__ void dev_bnprep(float* scal, int t) {
  if (t < 1024) {
    float sc = scal[SC_G2 + t] * (1.0f / sqrtf(scal[SC_V2 + t] + EPS_));
    scal[SC_ASC + t] = sc;
    scal[SC_ASH + t] = scal[SC_BA1 + t] * sc + (scal[SC_BT2 + t] - scal[SC_M2 + t] * sc);
  }
  if (t < 64) {
    float sc1 = scal[SC_G1 + t] * (1.0f / sqrtf(scal[SC_V1 + t] + EPS_));
    scal[SC_C1 + t] = scal[SC_BP1 + t] * sc1 + (scal[SC_BT1 + t] - scal[SC_M1 + t] * sc1);
    for (int i = 0; i < 3; i++) scal[SC_W1S + t * 3 + i] = scal[SC_WP1 + t * 3 + i] * sc1;
  }
}

struct C3 { const float* Wo[3]; const float* Wi[3]; const float* bi[3]; const float* bo[3];
            u16* Wout[3]; float* bout[3]; };
__device__ void dev_compose3(const C3& c, int z, int tid) {
  const float* Wo = c.Wo[z]; const float* Wi = c.Wi[z];
  if (tid < 256 * 128) {
    int o = tid >> 7, i = tid & 127;
    float a0 = 0.f, a1 = 0.f, a2 = 0.f, a3 = 0.f;
    for (int d = 0; d < 256; d += 4) {
      a0 += Wo[o * 256 + d + 0] * Wi[(d + 0) * 128 + i];
      a1 += Wo[o * 256 + d + 1] * Wi[(d + 1) * 128 + i];
      a2 += Wo[o * 256 + d + 2] * Wi[(d + 2) * 128 + i];
      a3 += Wo[o * 256 + d + 3] * Wi[(d + 3) * 128 + i];
    }
    c.Wout[z][o * 128 + i] = f2bu((a0 + a1) + (a2 + a3));
  } else if (tid < 256 * 128 + 256) {
    int o = tid - 256 * 128;
    float a = c.bo[z][o];
    for (int d = 0; d < 256; d++) a += Wo[o * 256 + d] * c.bi[z][d];
    c.bout[z][o] = a;
  }
}

struct QF { const float* src[3]; u16* dst[3]; int M[3]; int K[3]; };
__device__ void dev_quant_flin(const QF& q, int z, int g) {
  int M = q.M[z], K = q.K[z];
  if (g >= (M * K) / 8) return;
  int tile = g >> 6, lane = g & 63;
  int l15 = lane & 15, quad = lane >> 4;
  int kt = K >> 5;
  int mt = tile / kt, kc = tile % kt;
  const float* s = q.src[z] + (size_t)(mt * 16 + l15) * K + kc * 32 + quad * 8;
  u16* d = q.dst[z] + (size_t)g * 8;
  u16 o[8];
#pragma unroll
  for (int j = 0; j < 8; j++) o[j] = f2bu(s[j]);
  *(uint4*)d = *(uint4*)o;
}

struct T2 { const void* src[2]; u16* dst[2]; };
__device__ void dev_transq2(const T2& t2, int f, int bx, int by, int bz, int tid,
                            u16 (*t)[33]) {
  int tensor = bz >> 1, b = bz & 1;
  const void* raw = t2.src[tensor];
  u16* out = t2.dst[tensor];
  int c0 = by * 32, n0 = bx * 32;
  int j = tid & 31, i0 = tid >> 5;
  for (int s = 0; s < 32; s += 8) {
    int i = i0 + s;
    t[i][j] = f2bu(rdl(raw, ((size_t)b * 128 + c0 + i) * N_ + n0 + j, f));
  }
  __syncthreads();
  int i = tid & 31, j0 = tid >> 5;
  for (int s = 0; s < 32; s += 8) {
    int jj = j0 + s;
    out[((size_t)b * N_ + n0 + jj) * 128 + c0 + i] = t[i][jj];
  }
}

// ---------- KNN (bitonic networks) ----------
__device__ __forceinline__ u64 knn_key(const float* px, float qx, float qy, float qz,
                                       float sqn, int m) {
  float cx = px[m], cy = px[N_ + m], cz = px[2 * N_ + m];
  float sqm = cx * cx + cy * cy + cz * cz;
  float dot = qx * cx + qy * cy + qz * cz;
  float d = (sqn + sqm) - 2.0f * dot;
  unsigned ub = __float_as_uint(d);
  ub = ((int)ub < 0) ? ~ub : (ub | 0x80000000u);
  return ((u64)ub << 32) | (unsigned)m;
}

// full bitonic sort of 16 (ascending); all indices compile-time after unroll
__device__ __forceinline__ void bitonic_sort16(u64* c) {
#pragma unroll
  for (int k = 2; k <= 16; k <<= 1) {
#pragma unroll
    for (int j = k >> 1; j > 0; j >>= 1) {
#pragma unroll
      for (int i = 0; i < 16; i++) {
        int l = i ^ j;
        if (l > i) {
          u64 a = c[i], b2 = c[l];
          bool up = ((i & k) == 0);
          bool sw = up ? (b2 < a) : (a < b2);
          u64 na = sw ? b2 : a;
          u64 nb = sw ? a : b2;
          c[i] = na; c[l] = nb;
        }
      }
    }
  }
}

// best (sorted asc) := top-16 of best ∪ c, where c sorted asc.
__device__ __forceinline__ void bitonic_merge_into(u64* best, const u64* c) {
#pragma unroll
  for (int i = 0; i < 16; i++) {
    u64 b2 = c[15 - i];
    best[i] = (best[i] < b2) ? best[i] : b2;
  }
#pragma unroll
  for (int j = 8; j > 0; j >>= 1) {
#pragma unroll
    for (int i = 0; i < 16; i++) {
      if ((i & j) == 0) {
        u64 a = best[i], b2 = best[i | j];
        u64 mn = (a < b2) ? a : b2;
        u64 mx = (a < b2) ? b2 : a;
        best[i] = mn; best[i | j] = mx;
      }
    }
  }
}

__device__ void dev_knn_partial(const float* pos, u64* part, int tid) {
  int n = tid & (N_ - 1);
  int ch = (tid >> 12) & ((1 << LOGNCHK) - 1);
  int b = tid >> (12 + LOGNCHK);
  const float* px = pos + (size_t)b * 3 * N_;
  float qx = px[n], qy = px[N_ + n], qz = px[2 * N_ + n];
  float sqn = qx * qx + qy * qy + qz * qz;
  int clen = N_ >> LOGNCHK;    // 256, multiple of 16
  int m0 = ch * clen;
  u64 best[KNN];
  {
#pragma unroll
    for (int i = 0; i < 16; i++) best[i] = knn_key(px, qx, qy, qz, sqn, m0 + i);
    bitonic_sort16(best);
  }
  for (int m = m0 + 16; m < m0 + clen; m += 16) {
    u64 c[16];
#pragma unroll
    for (int i = 0; i < 16; i++) c[i] = knn_key(px, qx, qy, qz, sqn, m + i);
    bitonic_sort16(c);
    bitonic_merge_into(best, c);
  }
  u64* o = part + (size_t)tid * KNN;
#pragma unroll
  for (int i = 0; i < KNN; i++) o[i] = best[i];
}

__device__ void dev_knn_merge(const u64* part, int* idx, int tid) {
  if (tid >= B_ * N_) return;
  int n = tid & (N_ - 1);
  int b = tid >> 12;
  u64 best[KNN];
  {
    const u64* p = part + ((((size_t)(b << LOGNCHK)) << 12) + n) * KNN;
#pragma unroll
    for (int i = 0; i < KNN; i++) best[i] = p[i];
  }
  for (int ch = 1; ch < (1 << LOGNCHK); ch++) {
    const u64* p = part + ((((size_t)((b << LOGNCHK) + ch)) << 12) + n) * KNN;
    u64 c[16];
#pragma unroll
    for (int e = 0; e < KNN; e++) c[e] = p[e];
    bitonic_merge_into(best, c);   // lists already sorted asc
  }
  int* o = idx + (size_t)tid * KNN;
#pragma unroll
  for (int i = 0; i < KNN; i++) o[i] = (int)(best[i] & 0xffffffffu);
}

// ---------- gemm body (q/k/v projections, M=256, K=128) ----------
struct G3 { const u16* W[3]; const u16* Bsrc[3]; u16* O[3]; const float* bias[3]; };
__device__ void dev_gemm(const G3& g, int bx, int by, int bz, int tid,
                         u16* As, u16* Bs) {
  const int z = bz;
  const u16* Wg = g.W[z];
  const u16* Bg = g.Bsrc[z];
  u16* Out = g.O[z];
  const float* bias = g.bias[z];
  const int M = 256, K = 128;
  const int mtile = by, ctile = bx;
  const int wid = tid >> 6, lane = tid & 63;
  const int wm = wid >> 1, wc = wid & 1;
  const int l15 = lane & 15, quad = lane >> 4;
  f32x4 acc[4][4];
#pragma unroll
  for (int a = 0; a < 4; a++)
#pragma unroll
    for (int bb = 0; bb < 4; bb++) acc[a][bb] = (f32x4){0.f, 0.f, 0.f, 0.f};
  const int r0 = tid >> 2, q0 = tid & 3;
  for (int k0 = 0; k0 < K; k0 += 32) {
    __syncthreads();
    *(uint4*)(&As[(r0) * 32 + q0 * 8]) = *(const uint4*)(&Wg[((size_t)mtile * 128 + r0) * K + k0 + q0 * 8]);
    *(uint4*)(&As[(r0 + 64) * 32 + q0 * 8]) = *(const uint4*)(&Wg[((size_t)mtile * 128 + r0 + 64) * K + k0 + q0 * 8]);
    *(uint4*)(&Bs[(r0) * 32 + q0 * 8]) = *(const uint4*)(&Bg[((size_t)ctile * 128 + r0) * K + k0 + q0 * 8]);
    *(uint4*)(&Bs[(r0 + 64) * 32 + q0 * 8]) = *(const uint4*)(&Bg[((size_t)ctile * 128 + r0 + 64) * K + k0 + q0 * 8]);
    __syncthreads();
    bf16x8 af[4], bfr[4];
#pragma unroll
    for (int i = 0; i < 4; i++) {
      af[i] = *(const bf16x8*)(&As[(wm * 64 + i * 16 + l15) * 32 + quad * 8]);
      bfr[i] = *(const bf16x8*)(&Bs[(wc * 64 + i * 16 + l15) * 32 + quad * 8]);
    }
#pragma unroll
    for (int mi = 0; mi < 4; mi++)
#pragma unroll
      for (int ni = 0; ni < 4; ni++)
        acc[mi][ni] = __builtin_amdgcn_mfma_f32_16x16x32_bf16(af[mi], bfr[ni], acc[mi][ni], 0, 0, 0);
  }
  const int mbase = mtile * 128 + wm * 64;
  const int cbase = ctile * 128 + wc * 64;
#pragma unroll
  for (int mi = 0; mi < 4; mi++) {
#pragma unroll
    for (int ni = 0; ni < 4; ni++) {
      int m0 = mbase + mi * 16 + quad * 4;
      int c = cbase + ni * 16 + l15;
      u16 pk[4];
#pragma unroll
      for (int r = 0; r < 4; r++) pk[r] = f2bu(acc[mi][ni][r] + bias[m0 + r]);
      *(uint2*)(&Out[(size_t)c * M + m0]) = *(uint2*)pk;
    }
  }
}

// ---------- prepA: knn_partial | bnprep | compose3 | quant_flin | transq2 ----------
// ranges: [0,512) knn_partial, [512,516) bnprep, [516,906) compose3,
//         [906,1290) quant_flin (3 z x 128), [1290,3338) transq2
__global__ void prepA(C3 c3, QF qf, T2 t2, float* __restrict__ scal,
                      u64* __restrict__ knn_part, const int* __restrict__ flagp) {
  __shared__ u16 tq[32][33];
  int bid = blockIdx.x, tid = threadIdx.x;
  if (bid < 512) {
    dev_knn_partial(scal + SC_POS, knn_part, bid * 256 + tid);
  } else if (bid < 516) {
    dev_bnprep(scal, (bid - 512) * 256 + tid);
  } else if (bid < 906) {
    int u = bid - 516;
    dev_compose3(c3, u / 130, (u % 130) * 256 + tid);
  } else if (bid < 1290) {
    int u = bid - 906;
    dev_quant_flin(qf, u >> 7, (u & 127) * 256 + tid);
  } else {
    int u = bid - 1290;
    dev_transq2(t2, *flagp, u & 127, (u >> 7) & 3, u >> 9, tid, tq);
  }
}

// ---------- prepB: knn_merge | gemm_bt3 ----------
// ranges: [0,32) knn_merge, [32,416) gemm (bx=u&63, by=(u>>6)&1, bz=u>>7)
__global__ __launch_bounds__(256) void prepB(G3 g3, const u64* __restrict__ knn_part,
                                             int* __restrict__ idx) {
  __shared__ __align__(16) u16 As[128 * 32];
  __shared__ __align__(16) u16 Bs[128 * 32];
  int bid = blockIdx.x, tid = threadIdx.x;
  if (bid < 32) {
    dev_knn_merge(knn_part, idx, bid * 256 + tid);
  } else {
    int u = bid - 32;
    dev_gemm(g3, u & 63, (u >> 6) & 1, u >> 7, tid, As, Bs);
  }
}

// ================= MEGA v8: X fused into P1 epilogue (phase 2 deleted) =================
#define XS_OFF 0
#define HS_OFF 16896
#define AG_OFF 33792
#define SM_TOT 35872            // u16 -> 71,744 B -> 2 blocks/CU

__global__ __launch_bounds__(512, 4) void mega(
    const float* __restrict__ scal, const int* __restrict__ idx,
    const u16* __restrict__ query_t, const u16* __restrict__ key_t,
    const u16* __restrict__ value_t,
    float* __restrict__ out,
    const u16* __restrict__ Wp2f, const u16* __restrict__ Wa1f,
    const u16* __restrict__ Wa2f, const float* __restrict__ Wef) {
  __shared__ __align__(16) u16 sm[SM_TOT];
  float* aggs = (float*)&sm[AG_OFF];
  const int tid = threadIdx.x;
  const int w = tid >> 6, lane = tid & 63;
  const int l15 = lane & 15, quad = lane >> 4;
  const int gcol0 = blockIdx.x * 64;
  const int b = gcol0 >> 16;
  const int n0 = (gcol0 & 65535) >> 4;

  // ---- Prologue: q/k gathers in FRAGMENT layout (consumed by P1 epilogue).
  // For fragment (mi,ni): col = ni*16+l15 -> n = n0+ni (uniform), k = l15.
  // q read is 4 quads x 8B = 32B contiguous per (mi,ni); k is idx-gathered.
  uint2 qr[2][4], kr[2][4];
  {
    int id_c[4];
#pragma unroll
    for (int ni = 0; ni < 4; ni++)
      id_c[ni] = idx[((size_t)(b * N_ + n0 + ni)) * KNN + l15];
#pragma unroll
    for (int mi = 0; mi < 2; mi++)
#pragma unroll
      for (int ni = 0; ni < 4; ni++) {
        int m0 = w * 32 + mi * 16 + quad * 4;
        qr[mi][ni] = *(const uint2*)(query_t + ((size_t)(b * N_ + n0 + ni)) * D_ + m0);
        kr[mi][ni] = *(const uint2*)(key_t + ((size_t)(b * N_ + id_c[ni])) * D_ + m0);
      }
  }
  __builtin_amdgcn_sched_barrier(0);   // pin: loads issue HERE, not sunk into P1

  // ---- Phase 0: h1 -> HS ----
  {
    int col = tid >> 3, jg = (tid & 7) * 8;
    int n = n0 + (col >> 4), k = col & 15;
    int id = idx[((size_t)(b * N_ + n)) * KNN + k];
    const float* px = scal + SC_POS + (size_t)b * 3 * N_;
    float pr0 = px[n] - px[id];
    float pr1 = px[N_ + n] - px[N_ + id];
    float pr2 = px[2 * N_ + n] - px[2 * N_ + id];
    u16 o[8];
#pragma unroll
    for (int e = 0; e < 8; e++) {
      int j = jg + e;
      float v = scal[SC_W1S + j * 3] * pr0 + scal[SC_W1S + j * 3 + 1] * pr1 +
                scal[SC_W1S + j * 3 + 2] * pr2 + scal[SC_C1 + j];
      o[e] = f2bu(fmaxf(v, 0.f));
    }
    *(uint4*)(&sm[HS_OFF + col * 264 + jg]) = *(uint4*)o;
  }
  __syncthreads();

  // ---- Phase 1: P2 -> pe (regs); X = pe + q - k -> XS directly. K=64. ----
  uint2 pe_pk[2][4];
  {
    f32x4 pacc[2][4];
#pragma unroll
    for (int mi = 0; mi < 2; mi++)
#pragma unroll
      for (int ni = 0; ni < 4; ni++) pacc[mi][ni] = (f32x4){0.f, 0.f, 0.f, 0.f};
    __builtin_amdgcn_s_setprio(1);
#pragma unroll
    for (int kc = 0; kc < 2; kc++) {
      int k0 = kc * 32;
      bf16x8 af[2], bfr[4];
#pragma unroll
      for (int mi = 0; mi < 2; mi++)
        af[mi] = *(const bf16x8*)(Wp2f + (size_t)((w * 2 + mi) * 2 + kc) * 512 + lane * 8);
#pragma unroll
      for (int ni = 0; ni < 4; ni++)
        bfr[ni] = *(const bf16x8*)(&sm[HS_OFF + (ni * 16 + l15) * 264 + k0 + quad * 8]);
#pragma unroll
      for (int mi = 0; mi < 2; mi++)
#pragma unroll
        for (int ni = 0; ni < 4; ni++)
          pacc[mi][ni] = __builtin_amdgcn_mfma_f32_16x16x32_bf16(af[mi], bfr[ni], pacc[mi][ni], 0, 0, 0);
    }
    __builtin_amdgcn_s_setprio(0);
#pragma unroll
    for (int mi = 0; mi < 2; mi++)
#pragma unroll
      for (int ni = 0; ni < 4; ni++) {
        int m0 = w * 32 + mi * 16 + quad * 4;
        int col = ni * 16 + l15;
        const u16* qs = (const u16*)&qr[mi][ni];
        const u16* ks = (const u16*)&kr[mi][ni];
        u16 pkpe[4], pkx[4];
#pragma unroll
        for (int r = 0; r < 4; r++) {
          float pe = pacc[mi][ni][r] + scal[SC_BP2 + m0 + r];
          pkpe[r] = f2bu(pe);
          pkx[r] = f2bu(pe + (bu2f(qs[r]) - bu2f(ks[r])));
        }
        pe_pk[mi][ni] = *(uint2*)pkpe;
        *(uint2*)(&sm[XS_OFF + col * 264 + m0]) = *(uint2*)pkx;
      }
  }
  __syncthreads();

  // ---- A1/A2 over 4 hb slices of 256 rows ----
  f32x4 aacc[2][4];
#pragma unroll
  for (int mi = 0; mi < 2; mi++)
#pragma unroll
    for (int ni = 0; ni < 4; ni++) aacc[mi][ni] = (f32x4){0.f, 0.f, 0.f, 0.f};

  for (int hb = 0; hb < 4; hb++) {
    f32x4 hacc[2][4];
#pragma unroll
    for (int mi = 0; mi < 2; mi++)
#pragma unroll
      for (int ni = 0; ni < 4; ni++) hacc[mi][ni] = (f32x4){0.f, 0.f, 0.f, 0.f};
    __builtin_amdgcn_s_setprio(1);
#pragma unroll 4
    for (int kc = 0; kc < 8; kc++) {
      int k0 = kc * 32;
      bf16x8 af[2], bx[4];
#pragma unroll
      for (int mi = 0; mi < 2; mi++)
        af[mi] = *(const bf16x8*)(Wa1f + (size_t)((hb * 16 + w * 2 + mi) * 8 + kc) * 512 + lane * 8);
#pragma unroll
      for (int ni = 0; ni < 4; ni++)
        bx[ni] = *(const bf16x8*)(&sm[XS_OFF + (ni * 16 + l15) * 264 + k0 + quad * 8]);
#pragma unroll
      for (int mi = 0; mi < 2; mi++)
#pragma unroll
        for (int ni = 0; ni < 4; ni++)
          hacc[mi][ni] = __builtin_amdgcn_mfma_f32_16x16x32_bf16(af[mi], bx[ni], hacc[mi][ni], 0, 0, 0);
    }
    __builtin_amdgcn_s_setprio(0);
    __syncthreads();
#pragma unroll
    for (int mi = 0; mi < 2; mi++)
#pragma unroll
      for (int ni = 0; ni < 4; ni++) {
        int khb = w * 32 + mi * 16 + quad * 4;
        int mh = hb * 256 + khb;
        int col = ni * 16 + l15;
        u16 pk[4];
#pragma unroll
        for (int r = 0; r < 4; r++) {
          float v = hacc[mi][ni][r] * scal[SC_ASC + mh + r] + scal[SC_ASH + mh + r];
          pk[r] = f2bu(fmaxf(v, 0.f));
        }
        *(uint2*)(&sm[HS_OFF + col * 264 + khb]) = *(uint2*)pk;
      }
    __syncthreads();
    __builtin_amdgcn_s_setprio(1);
#pragma unroll 4
    for (int kc = 0; kc < 8; kc++) {
      int k0 = kc * 32;
      bf16x8 af[2], bh[4];
#pragma unroll
      for (int mi = 0; mi < 2; mi++)
        af[mi] = *(const bf16x8*)(Wa2f + (size_t)((w * 2 + mi) * 32 + hb * 8 + kc) * 512 + lane * 8);
#pragma unroll
      for (int ni = 0; ni < 4; ni++)
        bh[ni] = *(const bf16x8*)(&sm[HS_OFF + (ni * 16 + l15) * 264 + k0 + quad * 8]);
#pragma unroll
      for (int mi = 0; mi < 2; mi++)
#pragma unroll
        for (int ni = 0; ni < 4; ni++)
          aacc[mi][ni] = __builtin_amdgcn_mfma_f32_16x16x32_bf16(af[mi], bh[ni], aacc[mi][ni], 0, 0, 0);
    }
    __builtin_amdgcn_s_setprio(0);
  }

  // ---- Phase 5: attn (+ba2) -> XS ; pe (regs) -> HS ----
  __syncthreads();
#pragma unroll
  for (int mi = 0; mi < 2; mi++)
#pragma unroll
    for (int ni = 0; ni < 4; ni++) {
      int m0 = w * 32 + mi * 16 + quad * 4;
      int col = ni * 16 + l15;
      u16 pk[4];
#pragma unroll
      for (int r = 0; r < 4; r++) pk[r] = f2bu(aacc[mi][ni][r] + scal[SC_BA2 + m0 + r]);
      *(uint2*)(&sm[XS_OFF + col * 264 + m0]) = *(uint2*)pk;
      *(uint2*)(&sm[HS_OFF + col * 264 + m0]) = pe_pk[mi][ni];
    }
  __syncthreads();

  // ---- Phase 6: softmax + aggregate ----
#pragma unroll
  for (int it = 0; it < 2; it++) {
    int e = tid + it * 512;
    int pt = e >> 8, m = e & 255;
    float a[16];
#pragma unroll
    for (int k = 0; k < 16; k++) a[k] = bu2f(sm[XS_OFF + (pt * 16 + k) * 264 + m]);
    float t0 = fmaxf(a[0], a[1]),  t1 = fmaxf(a[2], a[3]);
    float t2 = fmaxf(a[4], a[5]),  t3 = fmaxf(a[6], a[7]);
    float t4 = fmaxf(a[8], a[9]),  t5 = fmaxf(a[10], a[11]);
    float t6 = fmaxf(a[12], a[13]), t7 = fmaxf(a[14], a[15]);
    t0 = fmaxf(t0, t1); t2 = fmaxf(t2, t3); t4 = fmaxf(t4, t5); t6 = fmaxf(t6, t7);
    float mx = fmaxf(fmaxf(t0, t2), fmaxf(t4, t6));
    float s = 0.f;
#pragma unroll
    for (int k = 0; k < 16; k++) { a[k] = __expf(a[k] - mx); s += a[k]; }
    float inv = __builtin_amdgcn_rcpf(s);
    float acc = 0.f;
#pragma unroll
    for (int k = 0; k < 16; k++)
      acc += a[k] * bu2f(sm[HS_OFF + (pt * 16 + k) * 264 + m]);
    float val = bu2f(value_t[((size_t)(b * N_ + n0 + pt)) * D_ + m]);
    aggs[pt * 260 + m] = fmaf(acc, inv, val);
  }
  __syncthreads();

  // ---- Phase 7: linear_end (f32 weights) ----
  {
    int ci = tid >> 2, pt = tid & 3;
    float acc = scal[SC_BFIN + ci];
    const float* wr = Wef + (size_t)ci * 256;
    const float* ag = aggs + pt * 260;
#pragma unroll 8
    for (int m4 = 0; m4 < 256; m4 += 4) {
      float4 wu = *(const float4*)(wr + m4);
      acc += wu.x * ag[m4] + wu.y * ag[m4 + 1] + wu.z * ag[m4 + 2] + wu.w * ag[m4 + 3];
    }
    out[((size_t)(b * 128 + ci)) * N_ + n0 + pt] = acc;
  }
}

// wtmp (f32) offsets
#define WT_LSQ 0
#define WT_LSO 32768
#define WT_K 65536
#define WT_Q 131072
#define WT_V 196608
#define WT_P2 262144
#define WT_A1 278528
#define WT_A2 540672
#define WT_TOT 802816
// wbf (bf16) offsets
#define WB_QP 0
#define WB_KP 32768
#define WB_VP 65536
#define WB_P2 98304
#define WB_A1 114688
#define WB_A2 376832
#define WB_TOT 638976

extern "C" void kernel_launch(void* const* d_in, const int* in_sizes, int n_in,
                              void* d_out, int out_size, void* d_ws, size_t ws_size,
                              hipStream_t stream) {
  (void)in_sizes; (void)n_in; (void)out_size; (void)ws_size;
  char* wsb = (char*)d_ws;
  size_t off = 0;
  auto alloc = [&](size_t bytes) -> void* {
    void* p = wsb + off;
    off = (off + bytes + 255) & ~(size_t)255;
    return p;
  };
  int* flag = (int*)alloc(256);
  int* idx = (int*)alloc((size_t)B_ * N_ * KNN * 4);
  u16* wbf = (u16*)alloc((size_t)WB_TOT * 2);
  float* scal = (float*)alloc((size_t)SC_TOT * 4);
  float* Wef = (float*)alloc((size_t)32768 * 4);
  u16* key_t = (u16*)alloc((size_t)B_ * N_ * D_ * 2);
  u16* query_t = (u16*)alloc((size_t)B_ * N_ * D_ * 2);
  u16* value_t = (u16*)alloc((size_t)B_ * N_ * D_ * 2);
  float* wtmp = (float*)alloc((size_t)WT_TOT * 4);              // dead after prepA
  u16* qp_t = (u16*)alloc((size_t)B_ * N_ * 128 * 2);           // dead after prepB
  u16* obj_t = (u16*)alloc((size_t)B_ * N_ * 128 * 2);          // dead after prepB
  u64* knn_part = (u64*)alloc(((size_t)(B_ * N_) << LOGNCHK) * KNN * 8);

  // ---- launch 1: ingest (inline dtype detect) ----
  SegTab st;
  int si = 0;
  auto seg = [&](int di, float* d, int n) { st.seg[si].s = d_in[di]; st.seg[si].d = d; st.seg[si].n = n; si++; };
  seg(1, scal + SC_POS, 24576);
  seg(4, scal + SC_BLSQ, 256); seg(6, scal + SC_BLSO, 256);
  seg(8, scal + SC_BK, 256); seg(10, scal + SC_BQ, 256); seg(12, scal + SC_BV, 256);
  seg(13, scal + SC_WP1, 192); seg(14, scal + SC_BP1, 64); seg(15, scal + SC_G1, 64);
  seg(16, scal + SC_BT1, 64); seg(17, scal + SC_M1, 64); seg(18, scal + SC_V1, 64);
  seg(20, scal + SC_BP2, 256); seg(22, scal + SC_BA1, 1024);
  seg(23, scal + SC_G2, 1024); seg(24, scal + SC_BT2, 1024); seg(25, scal + SC_M2, 1024);
  seg(26, scal + SC_V2, 1024); seg(28, scal + SC_BA2, 256); seg(30, scal + SC_BFIN, 128);
  seg(3, wtmp + WT_LSQ, 32768); seg(5, wtmp + WT_LSO, 32768);
  seg(7, wtmp + WT_K, 65536); seg(9, wtmp + WT_Q, 65536); seg(11, wtmp + WT_V, 65536);
  seg(19, wtmp + WT_P2, 16384); seg(21, wtmp + WT_A1, 262144);
  seg(27, wtmp + WT_A2, 262144); seg(29, Wef, 32768);
  int total = 32128 + WT_TOT + 32768;
  ingest<<<(total + 255) / 256, 256, 0, stream>>>(st, (const unsigned*)d_in[1], flag, total);

  // ---- launch 2: prepA ----
  C3 c3;
  c3.Wo[0] = wtmp + WT_Q; c3.Wi[0] = wtmp + WT_LSQ; c3.bi[0] = scal + SC_BLSQ; c3.bo[0] = scal + SC_BQ;
  c3.Wout[0] = wbf + WB_QP; c3.bout[0] = scal + SC_BQP;
  c3.Wo[1] = wtmp + WT_K; c3.Wi[1] = wtmp + WT_LSO; c3.bi[1] = scal + SC_BLSO; c3.bo[1] = scal + SC_BK;
  c3.Wout[1] = wbf + WB_KP; c3.bout[1] = scal + SC_BKP;
  c3.Wo[2] = wtmp + WT_V; c3.Wi[2] = wtmp + WT_LSO; c3.bi[2] = scal + SC_BLSO; c3.bo[2] = scal + SC_BV;
  c3.Wout[2] = wbf + WB_VP; c3.bout[2] = scal + SC_BVP;
  QF qf;
  qf.src[0] = wtmp + WT_P2; qf.dst[0] = wbf + WB_P2; qf.M[0] = 256;  qf.K[0] = 64;
  qf.src[1] = wtmp + WT_A1; qf.dst[1] = wbf + WB_A1; qf.M[1] = 1024; qf.K[1] = 256;
  qf.src[2] = wtmp + WT_A2; qf.dst[2] = wbf + WB_A2; qf.M[2] = 256;  qf.K[2] = 1024;
  T2 t2;
  t2.src[0] = d_in[2]; t2.dst[0] = qp_t;
  t2.src[1] = d_in[0]; t2.dst[1] = obj_t;
  prepA<<<3338, 256, 0, stream>>>(c3, qf, t2, scal, knn_part, flag);

  // ---- launch 3: prepB ----
  G3 g3;
  g3.W[0] = wbf + WB_QP; g3.Bsrc[0] = qp_t;  g3.O[0] = query_t; g3.bias[0] = scal + SC_BQP;
  g3.W[1] = wbf + WB_KP; g3.Bsrc[1] = obj_t; g3.O[1] = key_t;   g3.bias[1] = scal + SC_BKP;
  g3.W[2] = wbf + WB_VP; g3.Bsrc[2] = obj_t; g3.O[2] = value_t; g3.bias[2] = scal + SC_BVP;
  prepB<<<416, 256, 0, stream>>>(g3, knn_part, idx);

  // ---- launch 4: mega ----
  mega<<<COLS_TOTAL / 64, 512, 0, stream>>>(
      scal, idx, query_t, key_t, value_t, (float*)d_out,
      wbf + WB_P2, wbf + WB_A1, wbf + WB_A2, Wef);
}

// Round 9
// 378.534 us; speedup vs baseline: 1.1029x; 1.1029x over previous
//
#include <hip/hip_runtime.h>
#include <stdint.h>

#define B_ 2
#define N_ 4096
#define KNN 16
#define D_ 256
#define EPS_ 1e-5f
#define COLS_TOTAL (B_ * N_ * KNN)   // 131072
#define LOGNCHK 4

typedef unsigned short u16;
typedef unsigned long long u64;
typedef __bf16 bf16x8 __attribute__((ext_vector_type(8)));
typedef float f32x4 __attribute__((ext_vector_type(4)));

__device__ __forceinline__ float bu2f(u16 u) { return __uint_as_float(((unsigned)u) << 16); }
__device__ __forceinline__ u16 f2bu(float f) {
  __bf16 h = (__bf16)f;                      // RNE via v_cvt_pk_bf16_f32
  return __builtin_bit_cast(unsigned short, h);
}
__device__ __forceinline__ float rdl(const void* p, size_t i, int f) {
  return f ? bu2f(((const u16*)p)[i]) : ((const float*)p)[i];
}

// ---------- scal (canonical f32) offsets ----------
#define SC_POS 0
#define SC_BP2 24576
#define SC_BA2 24832
#define SC_BFIN 25088
#define SC_BQP 25216
#define SC_BKP 25472
#define SC_BVP 25728
#define SC_W1S 25984
#define SC_C1  26176
#define SC_ASC 26240
#define SC_ASH 27264
#define SC_TOT 28288

// ---------- per-block dtype detect (reads first 1KB of pos tensor) ----------
__device__ int block_flag(const unsigned* __restrict__ praw) {
  __shared__ int cnt;
  if (threadIdx.x == 0) cnt = 0;
  __syncthreads();
  if (threadIdx.x < 256) {
    unsigned wv = praw[threadIdx.x];
    unsigned e = (wv >> 7) & 0xFFu;
    if (e >= 0x7Au && e <= 0x81u) atomicAdd(&cnt, 1);
  }
  __syncthreads();
  return (cnt >= 128) ? 1 : 0;
}

// ---------- canon: raw -> f32 for arrays mega/prepB read ----------
#define NSEG 5
struct Seg { const void* s; float* d; int n; };
struct SegTab { Seg seg[NSEG]; };
#define CANON_TOT 57984   // 24576 + 256 + 256 + 128 + 32768
__device__ void dev_canon(const SegTab& t, int f, int gt) {
  if (gt >= CANON_TOT) return;
  int acc = 0, k = 0;
  for (k = 0; k < NSEG; k++) { if (gt < acc + t.seg[k].n) break; acc += t.seg[k].n; }
  t.seg[k].d[gt - acc] = rdl(t.seg[k].s, gt - acc, f);
}

// ---------- bnprep (raw inputs) ----------
struct BN { const void* ba1; const void* g2; const void* bt2; const void* m2; const void* v2;
            const void* wp1; const void* bp1; const void* g1; const void* bt1; const void* m1;
            const void* v1; };
__device__ void dev_bnprep(const BN& bn, float* scal, int t, int f) {
  if (t < 1024) {
    float sc = rdl(bn.g2, t, f) * (1.0f / sqrtf(rdl(bn.v2, t, f) + EPS_));
    scal[SC_ASC + t] = sc;
    scal[SC_ASH + t] = rdl(bn.ba1, t, f) * sc + (rdl(bn.bt2, t, f) - rdl(bn.m2, t, f) * sc);
  }
  if (t < 64) {
    float sc1 = rdl(bn.g1, t, f) * (1.0f / sqrtf(rdl(bn.v1, t, f) + EPS_));
    scal[SC_C1 + t] = rdl(bn.bp1, t, f) * sc1 + (rdl(bn.bt1, t, f) - rdl(bn.m1, t, f) * sc1);
    for (int i = 0; i < 3; i++) scal[SC_W1S + t * 3 + i] = rdl(bn.wp1, (size_t)t * 3 + i, f) * sc1;
  }
}

// ---------- compose3 (raw weights) ----------
struct C3 { const void* Wo[3]; const void* Wi[3]; const void* bi[3]; const void* bo[3];
            u16* Wout[3]; float* bout[3]; };
__device__ void dev_compose3(const C3& c, int z, int tid, int f) {
  if (tid < 256 * 128) {
    int o = tid >> 7, i = tid & 127;
    float a0 = 0.f, a1 = 0.f, a2 = 0.f, a3 = 0.f;
    if (f) {
      const u16* Wo = (const u16*)c.Wo[z]; const u16* Wi = (const u16*)c.Wi[z];
      for (int d = 0; d < 256; d += 4) {
        a0 += bu2f(Wo[o * 256 + d + 0]) * bu2f(Wi[(d + 0) * 128 + i]);
        a1 += bu2f(Wo[o * 256 + d + 1]) * bu2f(Wi[(d + 1) * 128 + i]);
        a2 += bu2f(Wo[o * 256 + d + 2]) * bu2f(Wi[(d + 2) * 128 + i]);
        a3 += bu2f(Wo[o * 256 + d + 3]) * bu2f(Wi[(d + 3) * 128 + i]);
      }
    } else {
      const float* Wo = (const float*)c.Wo[z]; const float* Wi = (const float*)c.Wi[z];
      for (int d = 0; d < 256; d += 4) {
        a0 += Wo[o * 256 + d + 0] * Wi[(d + 0) * 128 + i];
        a1 += Wo[o * 256 + d + 1] * Wi[(d + 1) * 128 + i];
        a2 += Wo[o * 256 + d + 2] * Wi[(d + 2) * 128 + i];
        a3 += Wo[o * 256 + d + 3] * Wi[(d + 3) * 128 + i];
      }
    }
    c.Wout[z][o * 128 + i] = f2bu((a0 + a1) + (a2 + a3));
  } else if (tid < 256 * 128 + 256) {
    int o = tid - 256 * 128;
    float a = rdl(c.bo[z], o, f);
    for (int d = 0; d < 256; d++) a += rdl(c.Wo[z], (size_t)o * 256 + d, f) * rdl(c.bi[z], d, f);
    c.bout[z][o] = a;
  }
}

// ---------- fragment-linear weight quantize (raw src) ----------
struct QF { const void* src[3]; u16* dst[3]; int M[3]; int K[3]; };
__device__ void dev_quant_flin(const QF& q, int z, int g, int f) {
  int M = q.M[z], K = q.K[z];
  if (g >= (M * K) / 8) return;
  int tile = g >> 6, lane = g & 63;
  int l15 = lane & 15, quad = lane >> 4;
  int kt = K >> 5;
  int mt = tile / kt, kc = tile % kt;
  size_t sb = (size_t)(mt * 16 + l15) * K + kc * 32 + quad * 8;
  u16* d = q.dst[z] + (size_t)g * 8;
  u16 o[8];
#pragma unroll
  for (int j = 0; j < 8; j++) o[j] = f2bu(rdl(q.src[z], sb + j, f));
  *(uint4*)d = *(uint4*)o;
}

// ---------- transpose+quantize ----------
struct T2 { const void* src[2]; u16* dst[2]; };
__device__ void dev_transq2(const T2& t2, int f, int bx, int by, int bz, int tid,
                            u16 (*t)[33]) {
  int tensor = bz >> 1, b = bz & 1;
  const void* raw = t2.src[tensor];
  u16* out = t2.dst[tensor];
  int c0 = by * 32, n0 = bx * 32;
  int j = tid & 31, i0 = tid >> 5;
  for (int s = 0; s < 32; s += 8) {
    int i = i0 + s;
    t[i][j] = f2bu(rdl(raw, ((size_t)b * 128 + c0 + i) * N_ + n0 + j, f));
  }
  __syncthreads();
  int i = tid & 31, j0 = tid >> 5;
  for (int s = 0; s < 32; s += 8) {
    int jj = j0 + s;
    out[((size_t)b * N_ + n0 + jj) * 128 + c0 + i] = t[i][jj];
  }
}

// ---------- KNN (bitonic networks; chunk staged in LDS) ----------
__device__ __forceinline__ u64 knn_key_lds(const float* c, float qx, float qy, float qz,
                                           float sqn, int j, int m0) {
  float cx = c[j], cy = c[256 + j], cz = c[512 + j];
  float sqm = cx * cx + cy * cy + cz * cz;
  float dot = qx * cx + qy * cy + qz * cz;
  float d = (sqn + sqm) - 2.0f * dot;
  unsigned ub = __float_as_uint(d);
  ub = ((int)ub < 0) ? ~ub : (ub | 0x80000000u);
  return ((u64)ub << 32) | (unsigned)(m0 + j);
}

__device__ __forceinline__ void bitonic_sort16(u64* c) {
#pragma unroll
  for (int k = 2; k <= 16; k <<= 1) {
#pragma unroll
    for (int j = k >> 1; j > 0; j >>= 1) {
#pragma unroll
      for (int i = 0; i < 16; i++) {
        int l = i ^ j;
        if (l > i) {
          u64 a = c[i], b2 = c[l];
          bool up = ((i & k) == 0);
          bool sw = up ? (b2 < a) : (a < b2);
          u64 na = sw ? b2 : a;
          u64 nb = sw ? a : b2;
          c[i] = na; c[l] = nb;
        }
      }
    }
  }
}

__device__ __forceinline__ void bitonic_merge_into(u64* best, const u64* c) {
#pragma unroll
  for (int i = 0; i < 16; i++) {
    u64 b2 = c[15 - i];
    best[i] = (best[i] < b2) ? best[i] : b2;
  }
#pragma unroll
  for (int j = 8; j > 0; j >>= 1) {
#pragma unroll
    for (int i = 0; i < 16; i++) {
      if ((i & j) == 0) {
        u64 a = best[i], b2 = best[i | j];
        u64 mn = (a < b2) ? a : b2;
        u64 mx = (a < b2) ? b2 : a;
        best[i] = mn; best[i | j] = mx;
      }
    }
  }
}

__device__ void dev_knn_partial(const void* pos_raw, int f, u64* part, int bid, int tid,
                                float* cpos) {
  int gtid = bid * 256 + tid;
  int n = gtid & (N_ - 1);
  int ch = (gtid >> 12) & ((1 << LOGNCHK) - 1);
  int b = gtid >> (12 + LOGNCHK);
  int clen = N_ >> LOGNCHK;    // 256 (all threads of block share chunk)
  int m0 = ch * clen;
  size_t base = (size_t)b * 3 * N_;
  cpos[tid]       = rdl(pos_raw, base + m0 + tid, f);
  cpos[256 + tid] = rdl(pos_raw, base + N_ + m0 + tid, f);
  cpos[512 + tid] = rdl(pos_raw, base + 2 * N_ + m0 + tid, f);
  float qx = rdl(pos_raw, base + n, f);
  float qy = rdl(pos_raw, base + N_ + n, f);
  float qz = rdl(pos_raw, base + 2 * N_ + n, f);
  __syncthreads();
  float sqn = qx * qx + qy * qy + qz * qz;
  u64 best[KNN];
  {
#pragma unroll
    for (int i = 0; i < 16; i++) best[i] = knn_key_lds(cpos, qx, qy, qz, sqn, i, m0);
    bitonic_sort16(best);
  }
  for (int j = 16; j < 256; j += 16) {
    u64 c[16];
#pragma unroll
    for (int i = 0; i < 16; i++) c[i] = knn_key_lds(cpos, qx, qy, qz, sqn, j + i, m0);
    bitonic_sort16(c);
    bitonic_merge_into(best, c);
  }
  u64* o = part + (size_t)gtid * KNN;
#pragma unroll
  for (int i = 0; i < KNN; i++) o[i] = best[i];
}

__device__ void dev_knn_merge(const u64* part, int* idx, int tid) {
  if (tid >= B_ * N_) return;
  int n = tid & (N_ - 1);
  int b = tid >> 12;
  u64 best[KNN];
  {
    const u64* p = part + ((((size_t)(b << LOGNCHK)) << 12) + n) * KNN;
#pragma unroll
    for (int i = 0; i < KNN; i++) best[i] = p[i];
  }
  for (int ch = 1; ch < (1 << LOGNCHK); ch++) {
    const u64* p = part + ((((size_t)((b << LOGNCHK) + ch)) << 12) + n) * KNN;
    u64 c[16];
#pragma unroll
    for (int e = 0; e < KNN; e++) c[e] = p[e];
    bitonic_merge_into(best, c);   // lists already sorted asc
  }
  int* o = idx + (size_t)tid * KNN;
#pragma unroll
  for (int i = 0; i < KNN; i++) o[i] = (int)(best[i] & 0xffffffffu);
}

// ---------- gemm body (q/k/v projections, M=256, K=128) ----------
struct G3 { const u16* W[3]; const u16* Bsrc[3]; u16* O[3]; const float* bias[3]; };
__device__ void dev_gemm(const G3& g, int bx, int by, int bz, int tid,
                         u16* As, u16* Bs) {
  const int z = bz;
  const u16* Wg = g.W[z];
  const u16* Bg = g.Bsrc[z];
  u16* Out = g.O[z];
  const float* bias = g.bias[z];
  const int M = 256, K = 128;
  const int mtile = by, ctile = bx;
  const int wid = tid >> 6, lane = tid & 63;
  const int wm = wid >> 1, wc = wid & 1;
  const int l15 = lane & 15, quad = lane >> 4;
  f32x4 acc[4][4];
#pragma unroll
  for (int a = 0; a < 4; a++)
#pragma unroll
    for (int bb = 0; bb < 4; bb++) acc[a][bb] = (f32x4){0.f, 0.f, 0.f, 0.f};
  const int r0 = tid >> 2, q0 = tid & 3;
  for (int k0 = 0; k0 < K; k0 += 32) {
    __syncthreads();
    *(uint4*)(&As[(r0) * 32 + q0 * 8]) = *(const uint4*)(&Wg[((size_t)mtile * 128 + r0) * K + k0 + q0 * 8]);
    *(uint4*)(&As[(r0 + 64) * 32 + q0 * 8]) = *(const uint4*)(&Wg[((size_t)mtile * 128 + r0 + 64) * K + k0 + q0 * 8]);
    *(uint4*)(&Bs[(r0) * 32 + q0 * 8]) = *(const uint4*)(&Bg[((size_t)ctile * 128 + r0) * K + k0 + q0 * 8]);
    *(uint4*)(&Bs[(r0 + 64) * 32 + q0 * 8]) = *(const uint4*)(&Bg[((size_t)ctile * 128 + r0 + 64) * K + k0 + q0 * 8]);
    __syncthreads();
    bf16x8 af[4], bfr[4];
#pragma unroll
    for (int i = 0; i < 4; i++) {
      af[i] = *(const bf16x8*)(&As[(wm * 64 + i * 16 + l15) * 32 + quad * 8]);
      bfr[i] = *(const bf16x8*)(&Bs[(wc * 64 + i * 16 + l15) * 32 + quad * 8]);
    }
#pragma unroll
    for (int mi = 0; mi < 4; mi++)
#pragma unroll
      for (int ni = 0; ni < 4; ni++)
        acc[mi][ni] = __builtin_amdgcn_mfma_f32_16x16x32_bf16(af[mi], bfr[ni], acc[mi][ni], 0, 0, 0);
  }
  const int mbase = mtile * 128 + wm * 64;
  const int cbase = ctile * 128 + wc * 64;
#pragma unroll
  for (int mi = 0; mi < 4; mi++) {
#pragma unroll
    for (int ni = 0; ni < 4; ni++) {
      int m0 = mbase + mi * 16 + quad * 4;
      int c = cbase + ni * 16 + l15;
      u16 pk[4];
#pragma unroll
      for (int r = 0; r < 4; r++) pk[r] = f2bu(acc[mi][ni][r] + bias[m0 + r]);
      *(uint2*)(&Out[(size_t)c * M + m0]) = *(uint2*)pk;
    }
  }
}

// ---------- prepA: knn_partial | transq2 | compose3 | quant_flin | bnprep | canon ----------
// ranges: [0,512) knn, [512,2560) transq2, [2560,2950) compose3,
//         [2950,3334) quant_flin, [3334,3338) bnprep, [3338,3565) canon
__global__ void prepA(C3 c3, QF qf, T2 t2, BN bn, SegTab st,
                      const void* __restrict__ pos_raw,
                      float* __restrict__ scal, u64* __restrict__ knn_part) {
  __shared__ float cpos[768];
  __shared__ u16 tq[32][33];
  int f = block_flag((const unsigned*)pos_raw);
  int bid = blockIdx.x, tid = threadIdx.x;
  if (bid < 512) {
    dev_knn_partial(pos_raw, f, knn_part, bid, tid, cpos);
  } else if (bid < 2560) {
    int u = bid - 512;
    dev_transq2(t2, f, u & 127, (u >> 7) & 3, u >> 9, tid, tq);
  } else if (bid < 2950) {
    int u = bid - 2560;
    dev_compose3(c3, u / 130, (u % 130) * 256 + tid, f);
  } else if (bid < 3334) {
    int u = bid - 2950;
    dev_quant_flin(qf, u >> 7, (u & 127) * 256 + tid, f);
  } else if (bid < 3338) {
    dev_bnprep(bn, scal, (bid - 3334) * 256 + tid, f);
  } else {
    dev_canon(st, f, (bid - 3338) * 256 + tid);
  }
}

// ---------- prepB: knn_merge | gemm_bt3 ----------
__global__ __launch_bounds__(256) void prepB(G3 g3, const u64* __restrict__ knn_part,
                                             int* __restrict__ idx) {
  __shared__ __align__(16) u16 As[128 * 32];
  __shared__ __align__(16) u16 Bs[128 * 32];
  int bid = blockIdx.x, tid = threadIdx.x;
  if (bid < 32) {
    dev_knn_merge(knn_part, idx, bid * 256 + tid);
  } else {
    int u = bid - 32;
    dev_gemm(g3, u & 63, (u >> 6) & 1, u >> 7, tid, As, Bs);
  }
}

// ================= MEGA (round-7 proven, 193us) =================
#define XS_OFF 0
#define HS_OFF 16896
#define AG_OFF 33792
#define SM_TOT 35872            // u16 -> 71,744 B -> 2 blocks/CU

__global__ __launch_bounds__(512, 4) void mega(
    const float* __restrict__ scal, const int* __restrict__ idx,
    const u16* __restrict__ query_t, const u16* __restrict__ key_t,
    const u16* __restrict__ value_t,
    float* __restrict__ out,
    const u16* __restrict__ Wp2f, const u16* __restrict__ Wa1f,
    const u16* __restrict__ Wa2f, const float* __restrict__ Wef) {
  __shared__ __align__(16) u16 sm[SM_TOT];
  float* aggs = (float*)&sm[AG_OFF];
  const int tid = threadIdx.x;
  const int w = tid >> 6, lane = tid & 63;
  const int l15 = lane & 15, quad = lane >> 4;
  const int gcol0 = blockIdx.x * 64;
  const int b = gcol0 >> 16;
  const int n0 = (gcol0 & 65535) >> 4;

  // ---- Prologue: issue P2's query/key gathers early ----
  uint4 qu_r[4], ku_r[4];
  {
#pragma unroll
    for (int it = 0; it < 4; it++) {
      int g = tid + it * 512;
      int col = g >> 5, dg = (g & 31) * 8;
      int n = n0 + (col >> 4), k = col & 15;
      int id = idx[((size_t)(b * N_ + n)) * KNN + k];
      qu_r[it] = *(const uint4*)(query_t + ((size_t)(b * N_ + n)) * D_ + dg);
      ku_r[it] = *(const uint4*)(key_t + ((size_t)(b * N_ + id)) * D_ + dg);
    }
  }

  // ---- Phase 0: h1 -> HS ----
  {
    int col = tid >> 3, jg = (tid & 7) * 8;
    int n = n0 + (col >> 4), k = col & 15;
    int id = idx[((size_t)(b * N_ + n)) * KNN + k];
    const float* px = scal + SC_POS + (size_t)b * 3 * N_;
    float pr0 = px[n] - px[id];
    float pr1 = px[N_ + n] - px[N_ + id];
    float pr2 = px[2 * N_ + n] - px[2 * N_ + id];
    u16 o[8];
#pragma unroll
    for (int e = 0; e < 8; e++) {
      int j = jg + e;
      float v = scal[SC_W1S + j * 3] * pr0 + scal[SC_W1S + j * 3 + 1] * pr1 +
                scal[SC_W1S + j * 3 + 2] * pr2 + scal[SC_C1 + j];
      o[e] = f2bu(fmaxf(v, 0.f));
    }
    *(uint4*)(&sm[HS_OFF + col * 264 + jg]) = *(uint4*)o;
  }
  __syncthreads();

  // ---- Phase 1: P2 -> pe into XS (packed copy kept in registers). K=64. ----
  uint2 pe_pk[2][4];
  {
    f32x4 pacc[2][4];
#pragma unroll
    for (int mi = 0; mi < 2; mi++)
#pragma unroll
      for (int ni = 0; ni < 4; ni++) pacc[mi][ni] = (f32x4){0.f, 0.f, 0.f, 0.f};
    __builtin_amdgcn_s_setprio(1);
#pragma unroll
    for (int kc = 0; kc < 2; kc++) {
      int k0 = kc * 32;
      bf16x8 af[2], bfr[4];
#pragma unroll
      for (int mi = 0; mi < 2; mi++)
        af[mi] = *(const bf16x8*)(Wp2f + (size_t)((w * 2 + mi) * 2 + kc) * 512 + lane * 8);
#pragma unroll
      for (int ni = 0; ni < 4; ni++)
        bfr[ni] = *(const bf16x8*)(&sm[HS_OFF + (ni * 16 + l15) * 264 + k0 + quad * 8]);
#pragma unroll
      for (int mi = 0; mi < 2; mi++)
#pragma unroll
        for (int ni = 0; ni < 4; ni++)
          pacc[mi][ni] = __builtin_amdgcn_mfma_f32_16x16x32_bf16(af[mi], bfr[ni], pacc[mi][ni], 0, 0, 0);
    }
    __builtin_amdgcn_s_setprio(0);
#pragma unroll
    for (int mi = 0; mi < 2; mi++)
#pragma unroll
      for (int ni = 0; ni < 4; ni++) {
        int m0 = w * 32 + mi * 16 + quad * 4;
        int col = ni * 16 + l15;
        u16 pk[4];
#pragma unroll
        for (int r = 0; r < 4; r++) pk[r] = f2bu(pacc[mi][ni][r] + scal[SC_BP2 + m0 + r]);
        uint2 pu = *(uint2*)pk;
        pe_pk[mi][ni] = pu;
        *(uint2*)(&sm[XS_OFF + col * 264 + m0]) = pu;
      }
  }
  __syncthreads();

  // ---- Phase 2: X = query - key_gather + pe -> XS (gathers pre-issued) ----
  {
    uint4 xbuf[4];
#pragma unroll
    for (int it = 0; it < 4; it++) {
      int g = tid + it * 512;
      int col = g >> 5, dg = (g & 31) * 8;
      uint4 pu = *(const uint4*)(&sm[XS_OFF + col * 264 + dg]);
      const u16 *qs = (const u16*)&qu_r[it], *ks = (const u16*)&ku_r[it], *ps = (const u16*)&pu;
      u16 o[8];
#pragma unroll
      for (int e = 0; e < 8; e++) o[e] = f2bu((bu2f(qs[e]) - bu2f(ks[e])) + bu2f(ps[e]));
      xbuf[it] = *(uint4*)o;
    }
    __syncthreads();
#pragma unroll
    for (int it = 0; it < 4; it++) {
      int g = tid + it * 512;
      int col = g >> 5, dg = (g & 31) * 8;
      *(uint4*)(&sm[XS_OFF + col * 264 + dg]) = xbuf[it];
    }
  }
  __syncthreads();

  // ---- A1/A2 over 4 hb slices of 256 rows ----
  f32x4 aacc[2][4];
#pragma unroll
  for (int mi = 0; mi < 2; mi++)
#pragma unroll
    for (int ni = 0; ni < 4; ni++) aacc[mi][ni] = (f32x4){0.f, 0.f, 0.f, 0.f};

  for (int hb = 0; hb < 4; hb++) {
    f32x4 hacc[2][4];
#pragma unroll
    for (int mi = 0; mi < 2; mi++)
#pragma unroll
      for (int ni = 0; ni < 4; ni++) hacc[mi][ni] = (f32x4){0.f, 0.f, 0.f, 0.f};
    __builtin_amdgcn_s_setprio(1);
#pragma unroll 4
    for (int kc = 0; kc < 8; kc++) {
      int k0 = kc * 32;
      bf16x8 af[2], bx[4];
#pragma unroll
      for (int mi = 0; mi < 2; mi++)
        af[mi] = *(const bf16x8*)(Wa1f + (size_t)((hb * 16 + w * 2 + mi) * 8 + kc) * 512 + lane * 8);
#pragma unroll
      for (int ni = 0; ni < 4; ni++)
        bx[ni] = *(const bf16x8*)(&sm[XS_OFF + (ni * 16 + l15) * 264 + k0 + quad * 8]);
#pragma unroll
      for (int mi = 0; mi < 2; mi++)
#pragma unroll
        for (int ni = 0; ni < 4; ni++)
          hacc[mi][ni] = __builtin_amdgcn_mfma_f32_16x16x32_bf16(af[mi], bx[ni], hacc[mi][ni], 0, 0, 0);
    }
    __builtin_amdgcn_s_setprio(0);
    __syncthreads();
#pragma unroll
    for (int mi = 0; mi < 2; mi++)
#pragma unroll
      for (int ni = 0; ni < 4; ni++) {
        int khb = w * 32 + mi * 16 + quad * 4;
        int mh = hb * 256 + khb;
        int col = ni * 16 + l15;
        u16 pk[4];
#pragma unroll
        for (int r = 0; r < 4; r++) {
          float v = hacc[mi][ni][r] * scal[SC_ASC + mh + r] + scal[SC_ASH + mh + r];
          pk[r] = f2bu(fmaxf(v, 0.f));
        }
        *(uint2*)(&sm[HS_OFF + col * 264 + khb]) = *(uint2*)pk;
      }
    __syncthreads();
    __builtin_amdgcn_s_setprio(1);
#pragma unroll 4
    for (int kc = 0; kc < 8; kc++) {
      int k0 = kc * 32;
      bf16x8 af[2], bh[4];
#pragma unroll
      for (int mi = 0; mi < 2; mi++)
        af[mi] = *(const bf16x8*)(Wa2f + (size_t)((w * 2 + mi) * 32 + hb * 8 + kc) * 512 + lane * 8);
#pragma unroll
      for (int ni = 0; ni < 4; ni++)
        bh[ni] = *(const bf16x8*)(&sm[HS_OFF + (ni * 16 + l15) * 264 + k0 + quad * 8]);
#pragma unroll
      for (int mi = 0; mi < 2; mi++)
#pragma unroll
        for (int ni = 0; ni < 4; ni++)
          aacc[mi][ni] = __builtin_amdgcn_mfma_f32_16x16x32_bf16(af[mi], bh[ni], aacc[mi][ni], 0, 0, 0);
    }
    __builtin_amdgcn_s_setprio(0);
  }

  // ---- Phase 5: attn (+ba2) -> XS ; pe (regs) -> HS ----
  __syncthreads();
#pragma unroll
  for (int mi = 0; mi < 2; mi++)
#pragma unroll
    for (int ni = 0; ni < 4; ni++) {
      int m0 = w * 32 + mi * 16 + quad * 4;
      int col = ni * 16 + l15;
      u16 pk[4];
#pragma unroll
      for (int r = 0; r < 4; r++) pk[r] = f2bu(aacc[mi][ni][r] + scal[SC_BA2 + m0 + r]);
      *(uint2*)(&sm[XS_OFF + col * 264 + m0]) = *(uint2*)pk;
      *(uint2*)(&sm[HS_OFF + col * 264 + m0]) = pe_pk[mi][ni];
    }
  __syncthreads();

  // ---- Phase 6: softmax + aggregate ----
#pragma unroll
  for (int it = 0; it < 2; it++) {
    int e = tid + it * 512;
    int pt = e >> 8, m = e & 255;
    float a[16];
#pragma unroll
    for (int k = 0; k < 16; k++) a[k] = bu2f(sm[XS_OFF + (pt * 16 + k) * 264 + m]);
    float t0 = fmaxf(a[0], a[1]),  t1 = fmaxf(a[2], a[3]);
    float t2 = fmaxf(a[4], a[5]),  t3 = fmaxf(a[6], a[7]);
    float t4 = fmaxf(a[8], a[9]),  t5 = fmaxf(a[10], a[11]);
    float t6 = fmaxf(a[12], a[13]), t7 = fmaxf(a[14], a[15]);
    t0 = fmaxf(t0, t1); t2 = fmaxf(t2, t3); t4 = fmaxf(t4, t5); t6 = fmaxf(t6, t7);
    float mx = fmaxf(fmaxf(t0, t2), fmaxf(t4, t6));
    float s = 0.f;
#pragma unroll
    for (int k = 0; k < 16; k++) { a[k] = __expf(a[k] - mx); s += a[k]; }
    float inv = __builtin_amdgcn_rcpf(s);
    float acc = 0.f;
#pragma unroll
    for (int k = 0; k < 16; k++)
      acc += a[k] * bu2f(sm[HS_OFF + (pt * 16 + k) * 264 + m]);
    float val = bu2f(value_t[((size_t)(b * N_ + n0 + pt)) * D_ + m]);
    aggs[pt * 260 + m] = fmaf(acc, inv, val);
  }
  __syncthreads();

  // ---- Phase 7: linear_end (f32 weights) ----
  {
    int ci = tid >> 2, pt = tid & 3;
    float acc = scal[SC_BFIN + ci];
    const float* wr = Wef + (size_t)ci * 256;
    const float* ag = aggs + pt * 260;
#pragma unroll 8
    for (int m4 = 0; m4 < 256; m4 += 4) {
      float4 wu = *(const float4*)(wr + m4);
      acc += wu.x * ag[m4] + wu.y * ag[m4 + 1] + wu.z * ag[m4 + 2] + wu.w * ag[m4 + 3];
    }
    out[((size_t)(b * 128 + ci)) * N_ + n0 + pt] = acc;
  }
}

// wbf (bf16) offsets
#define WB_QP 0
#define WB_KP 32768
#define WB_VP 65536
#define WB_P2 98304
#define WB_A1 114688
#define WB_A2 376832
#define WB_TOT 638976

extern "C" void kernel_launch(void* const* d_in, const int* in_sizes, int n_in,
                              void* d_out, int out_size, void* d_ws, size_t ws_size,
                              hipStream_t stream) {
  (void)in_sizes; (void)n_in; (void)out_size; (void)ws_size;
  char* wsb = (char*)d_ws;
  size_t off = 0;
  auto alloc = [&](size_t bytes) -> void* {
    void* p = wsb + off;
    off = (off + bytes + 255) & ~(size_t)255;
    return p;
  };
  int* idx = (int*)alloc((size_t)B_ * N_ * KNN * 4);
  u16* wbf = (u16*)alloc((size_t)WB_TOT * 2);
  float* scal = (float*)alloc((size_t)SC_TOT * 4);
  float* Wef = (float*)alloc((size_t)32768 * 4);
  u16* key_t = (u16*)alloc((size_t)B_ * N_ * D_ * 2);
  u16* query_t = (u16*)alloc((size_t)B_ * N_ * D_ * 2);
  u16* value_t = (u16*)alloc((size_t)B_ * N_ * D_ * 2);
  u16* qp_t = (u16*)alloc((size_t)B_ * N_ * 128 * 2);           // dead after prepB
  u16* obj_t = (u16*)alloc((size_t)B_ * N_ * 128 * 2);          // dead after prepB
  u64* knn_part = (u64*)alloc(((size_t)(B_ * N_) << LOGNCHK) * KNN * 8);

  // ---- launch 1: prepA (raw-input readers; per-block dtype flag) ----
  C3 c3;
  c3.Wo[0] = d_in[9];  c3.Wi[0] = d_in[3]; c3.bi[0] = d_in[4]; c3.bo[0] = d_in[10];
  c3.Wout[0] = wbf + WB_QP; c3.bout[0] = scal + SC_BQP;
  c3.Wo[1] = d_in[7];  c3.Wi[1] = d_in[5]; c3.bi[1] = d_in[6]; c3.bo[1] = d_in[8];
  c3.Wout[1] = wbf + WB_KP; c3.bout[1] = scal + SC_BKP;
  c3.Wo[2] = d_in[11]; c3.Wi[2] = d_in[5]; c3.bi[2] = d_in[6]; c3.bo[2] = d_in[12];
  c3.Wout[2] = wbf + WB_VP; c3.bout[2] = scal + SC_BVP;
  QF qf;
  qf.src[0] = d_in[19]; qf.dst[0] = wbf + WB_P2; qf.M[0] = 256;  qf.K[0] = 64;
  qf.src[1] = d_in[21]; qf.dst[1] = wbf + WB_A1; qf.M[1] = 1024; qf.K[1] = 256;
  qf.src[2] = d_in[27]; qf.dst[2] = wbf + WB_A2; qf.M[2] = 256;  qf.K[2] = 1024;
  T2 t2;
  t2.src[0] = d_in[2]; t2.dst[0] = qp_t;
  t2.src[1] = d_in[0]; t2.dst[1] = obj_t;
  BN bn;
  bn.ba1 = d_in[22]; bn.g2 = d_in[23]; bn.bt2 = d_in[24]; bn.m2 = d_in[25]; bn.v2 = d_in[26];
  bn.wp1 = d_in[13]; bn.bp1 = d_in[14]; bn.g1 = d_in[15]; bn.bt1 = d_in[16]; bn.m1 = d_in[17];
  bn.v1 = d_in[18];
  SegTab st;
  st.seg[0] = {d_in[1],  scal + SC_POS,  24576};
  st.seg[1] = {d_in[20], scal + SC_BP2,  256};
  st.seg[2] = {d_in[28], scal + SC_BA2,  256};
  st.seg[3] = {d_in[30], scal + SC_BFIN, 128};
  st.seg[4] = {d_in[29], Wef,            32768};
  prepA<<<3565, 256, 0, stream>>>(c3, qf, t2, bn, st, d_in[1], scal, knn_part);

  // ---- launch 2: prepB ----
  G3 g3;
  g3.W[0] = wbf + WB_QP; g3.Bsrc[0] = qp_t;  g3.O[0] = query_t; g3.bias[0] = scal + SC_BQP;
  g3.W[1] = wbf + WB_KP; g3.Bsrc[1] = obj_t; g3.O[1] = key_t;   g3.bias[1] = scal + SC_BKP;
  g3.W[2] = wbf + WB_VP; g3.Bsrc[2] = obj_t; g3.O[2] = value_t; g3.bias[2] = scal + SC_BVP;
  prepB<<<416, 256, 0, stream>>>(g3, knn_part, idx);

  // ---- launch 3: mega ----
  mega<<<COLS_TOTAL / 64, 512, 0, stream>>>(
      scal, idx, query_t, key_t, value_t, (float*)d_out,
      wbf + WB_P2, wbf + WB_A1, wbf + WB_A2, Wef);
}